// Round 13
// baseline (3496.431 us; speedup 1.0000x reference)
//
#include <hip/hip_runtime.h>
#include <hip/hip_bf16.h>

// DelayRNN on MI355X — Round 13.
// Batch-group pipelining on the R5/R12 core: B=32 = 32 independent chains.
// Two groups of 16 rows interleave phases on the same 32 WGs, so group A's
// exchange RTT propagates during group B's compute and vice versa:
// period = max(2W', RTT + W') instead of W + RTT. Tagged self-validating
// words (no producer barrier), per-group ping-pong, 32KB poll images.
// GEMM switches to 12 (matrix, K-half) units over 4 waves so total B-bytes
// per step are unchanged; K-half partials summed in the epilogue (R2 pattern).

constexpr int kB    = 32;
constexpr int kS    = 256;
constexpr int kI    = 128;
constexpr int kH    = 512;
constexpr int kC    = 64;
constexpr int kOutL = 64;
constexpr int kMaxD = 16;
constexpr int kBufD = 17;
constexpr int kNWG  = 32;
constexpr int kJPW  = 16;
constexpr int kGB   = 16;            // batch rows per group
constexpr int kSteps = kS + kOutL;   // 320
constexpr int kKz   = kH + kI;       // 640
constexpr int kZPad = 8;             // zs row stride 648 elem (1296 B)

typedef __bf16 bf16x8 __attribute__((ext_vector_type(8)));
typedef float  f32x4  __attribute__((ext_vector_type(4)));
typedef unsigned int u32x4 __attribute__((ext_vector_type(4)));

__device__ __forceinline__ f32x4 MFMA(bf16x8 a, bf16x8 b, f32x4 c) {
  return __builtin_amdgcn_mfma_f32_16x16x32_bf16(a, b, c, 0, 0, 0);
}
__device__ __forceinline__ bf16x8 ld8(const __hip_bfloat16* p) {
  return *reinterpret_cast<const bf16x8*>(p);
}
__device__ __forceinline__ bf16x8 ld8_f32(const float* p) {
  float4 a = *(const float4*)p, b = *(const float4*)(p + 4);
  union { __hip_bfloat16 h[8]; bf16x8 v; } c;
  c.h[0] = __float2bfloat16(a.x); c.h[1] = __float2bfloat16(a.y);
  c.h[2] = __float2bfloat16(a.z); c.h[3] = __float2bfloat16(a.w);
  c.h[4] = __float2bfloat16(b.x); c.h[5] = __float2bfloat16(b.y);
  c.h[6] = __float2bfloat16(b.z); c.h[7] = __float2bfloat16(b.w);
  return c.v;
}
__device__ __forceinline__ float sigm(float x) { return 1.0f / (1.0f + __expf(-x)); }

// ---------------- prep kernels (validated R2-R12) ----------------

__global__ void prep_cast(const float* x, const float* W_in, const float* W_pass,
                          const float* W_tau, const float* W_mem, const float* W_out,
                          __hip_bfloat16* xb, __hip_bfloat16* Wall, __hip_bfloat16* BtP,
                          __hip_bfloat16* BtT, __hip_bfloat16* BtM, __hip_bfloat16* WtOut) {
  const int tid = blockIdx.x * blockDim.x + threadIdx.x;
  const int nth = gridDim.x * blockDim.x;
  for (int i = tid; i < kB * kS * kI; i += nth) xb[i] = __float2bfloat16(x[i]);
  for (int i = tid; i < kH * kKz; i += nth) {
    int j = i / kKz, k = i - j * kKz;
    Wall[i] = __float2bfloat16(W_in[k * kH + j]);
  }
  for (int i = tid; i < kH * kH; i += nth) {
    int j = i >> 9, k = i & 511;
    BtP[i] = __float2bfloat16(W_pass[k * kH + j]);
    BtT[i] = __float2bfloat16(W_tau[k * kH + j]);
    BtM[i] = __float2bfloat16(W_mem[k * kH + j]);
  }
  for (int i = tid; i < kC * kH; i += nth) {
    int c = i >> 9, k = i & 511;
    WtOut[i] = __float2bfloat16(W_out[k * kC + c]);
  }
}

__global__ void prep_bias(const float* b_in, const float* b_pass, const float* b_tau,
                          const float* b_mem, const float* W_pass, const float* W_tau,
                          const float* W_mem, float* bias) {
  __shared__ float bp_s[kH];
  const int j = threadIdx.x;
  float s1 = 0.f, s2 = 0.f, s3 = 0.f;
  for (int k = 0; k < kH; ++k) {
    float bi = b_in[k];
    s1 += bi * W_pass[k * kH + j];
    s2 += bi * W_tau[k * kH + j];
    s3 += bi * W_mem[k * kH + j];
  }
  float bP = s1 + b_pass[j];
  bias[j]          = b_in[j];
  bias[kH + j]     = bP;
  bias[2 * kH + j] = s2 + b_tau[j];
  bias[4 * kH + j] = s3 + b_mem[j];
  bp_s[j] = bP;
  __syncthreads();
  float s4 = 0.f, s5 = 0.f;
  for (int k = 0; k < kH; ++k) {
    float v = bp_s[k];
    s4 += v * W_tau[k * kH + j];
    s5 += v * W_mem[k * kH + j];
  }
  bias[3 * kH + j] = s4 + b_tau[j];
  bias[5 * kH + j] = s5 + b_mem[j];
}

__global__ __launch_bounds__(64) void prep_mm1(const float* W_in, const __hip_bfloat16* BtP,
    const __hip_bfloat16* BtT, const __hip_bfloat16* BtM,
    __hip_bfloat16* Wall, __hip_bfloat16* Cip) {
  const int bm = blockIdx.x, bn = blockIdx.y, z = blockIdx.z;
  const int lane = threadIdx.x;
  const int kq = (lane >> 4) * 8;
  const __hip_bfloat16* Bt = (z == 0) ? BtP : (z == 1 ? BtT : BtM);
  const int mat = (z == 0) ? 1 : (z == 1 ? 2 : 4);
  const float* arow = W_in + (size_t)(bm * 16 + (lane & 15)) * kH;
  const __hip_bfloat16* brow = Bt + (size_t)(bn * 16 + (lane & 15)) * kH;
  f32x4 acc = {0.f, 0.f, 0.f, 0.f};
  for (int i = 0; i < 16; ++i) {
    const int kk = i * 32 + kq;
    acc = MFMA(ld8_f32(arow + kk), ld8(brow + kk), acc);
  }
  const int rm = (lane >> 4) * 4, cn = lane & 15;
  union { __hip_bfloat16 h[4]; ushort4 s; } cv;
#pragma unroll
  for (int r = 0; r < 4; ++r) cv.h[r] = __float2bfloat16(acc[r]);
  __hip_bfloat16* wd = Wall + ((size_t)mat * kH + bn * 16 + cn) * kKz + bm * 16 + rm;
  *(ushort4*)wd = cv.s;
  if (z == 0) {
#pragma unroll
    for (int r = 0; r < 4; ++r)
      Cip[(size_t)(bm * 16 + rm + r) * kH + bn * 16 + cn] = cv.h[r];
  }
}

__global__ __launch_bounds__(64) void prep_mm2(const __hip_bfloat16* Cip,
    const __hip_bfloat16* BtT, const __hip_bfloat16* BtM, __hip_bfloat16* Wall) {
  const int bm = blockIdx.x, bn = blockIdx.y, z = blockIdx.z;
  const int lane = threadIdx.x;
  const int kq = (lane >> 4) * 8;
  const __hip_bfloat16* Bt = (z == 0) ? BtT : BtM;
  const int mat = (z == 0) ? 3 : 5;
  const __hip_bfloat16* arow = Cip + (size_t)(bm * 16 + (lane & 15)) * kH;
  const __hip_bfloat16* brow = Bt + (size_t)(bn * 16 + (lane & 15)) * kH;
  f32x4 acc = {0.f, 0.f, 0.f, 0.f};
  for (int i = 0; i < 16; ++i) {
    const int kk = i * 32 + kq;
    acc = MFMA(ld8(arow + kk), ld8(brow + kk), acc);
  }
  const int rm = (lane >> 4) * 4, cn = lane & 15;
  union { __hip_bfloat16 h[4]; ushort4 s; } cv;
#pragma unroll
  for (int r = 0; r < 4; ++r) cv.h[r] = __float2bfloat16(acc[r]);
  __hip_bfloat16* wd = Wall + ((size_t)mat * kH + bn * 16 + cn) * kKz + bm * 16 + rm;
  *(ushort4*)wd = cv.s;
}

// ---------------- main persistent kernel ----------------

struct KParams {
  const __hip_bfloat16* xb;       // bf16 input [B][S][I]
  const __hip_bfloat16* Wall;     // [6][512][640] composites, [col][k]
  const __hip_bfloat16* WtOut;    // [64][512]
  const float* bias;              // [6][512]
  const float* b_out;             // [64]
  unsigned* hg;                   // [2 group][2 parity][16][512] tagged words
  __hip_bfloat16* h0hist;         // [64][32][512] decode-entry snapshots
  int* arrive;                    // tail-barrier flags, 64B stride
  const int* lengths;
  float* dout;                    // [B][kOutL][C]
};

__global__ __launch_bounds__(256, 1) void rnn_main(KParams P) {
  __shared__ __align__(16) __hip_bfloat16 zs[kGB][kKz + kZPad];  // 20,736 B
  __shared__ float outLDS[6][2][kGB][kJPW + 1];                  // 13,056 B
  __shared__ int   len_s[kB];

  const int wg = blockIdx.x, tid = threadIdx.x;
  const int lane = tid & 63, wave = tid >> 6;
  const int q = lane >> 4, r = lane & 15;
  const int kq = q * 8;
  const int jn = wg * kJPW + r;
  // 12 units of (matrix, K-half) over 4 waves, 3 per wave.
  const __hip_bfloat16* Wb[3];
  int khs[3], ums[3];
#pragma unroll
  for (int s = 0; s < 3; ++s) {
    const int u = 3 * wave + s;
    ums[s] = u >> 1; khs[s] = u & 1;
    Wb[s] = P.Wall + ((size_t)ums[s] * kH + jn) * kKz + khs[s] * 320;
  }
  const int eb2 = tid >> 4, ec = tid & 15;    // epilogue: group-row, col
  const int j = wg * kJPW + ec;

  float bufr[2][kBufD];
#pragma unroll
  for (int u = 0; u < 2; ++u)
#pragma unroll
    for (int d = 0; d < kBufD; ++d) bufr[u][d] = 0.f;

  if (tid < kB) len_s[tid] = P.lengths[tid];
  __syncthreads();

  const unsigned o0 = tid * 16u;   // poll byte offset within 32KB image

  for (int t = 0; t < kSteps; ++t) {
#pragma unroll
    for (int g = 0; g < 2; ++g) {
      const unsigned* hr = P.hg + ((size_t)(g * 2 + (t & 1)) * 8192);
      unsigned*       hw = P.hg + ((size_t)(g * 2 + ((t + 1) & 1)) * 8192);

      // ---- fused detect+fetch: poll 32KB tagged image until tags == t ----
      {
        const unsigned tga = ((unsigned)t) << 16;
        u32x4 c0, c1, c2, c3, c4, c5, c6, c7;
        for (;;) {
          asm volatile(
              "global_load_dwordx4 %0, %8, %16 sc0 sc1\n\t"
              "global_load_dwordx4 %1, %9, %16 sc0 sc1\n\t"
              "global_load_dwordx4 %2, %10, %16 sc0 sc1\n\t"
              "global_load_dwordx4 %3, %11, %16 sc0 sc1\n\t"
              "global_load_dwordx4 %4, %12, %16 sc0 sc1\n\t"
              "global_load_dwordx4 %5, %13, %16 sc0 sc1\n\t"
              "global_load_dwordx4 %6, %14, %16 sc0 sc1\n\t"
              "global_load_dwordx4 %7, %15, %16 sc0 sc1\n\t"
              "s_waitcnt vmcnt(0)"
              : "=&v"(c0), "=&v"(c1), "=&v"(c2), "=&v"(c3),
                "=&v"(c4), "=&v"(c5), "=&v"(c6), "=&v"(c7)
              : "v"(o0), "v"(o0 + 4096u), "v"(o0 + 8192u), "v"(o0 + 12288u),
                "v"(o0 + 16384u), "v"(o0 + 20480u), "v"(o0 + 24576u), "v"(o0 + 28672u),
                "s"(hr)
              : "memory");
          // each 4B word independently tagged (4B atomic publish)
          unsigned bad =
              (c0.x ^ tga) | (c0.y ^ tga) | (c0.z ^ tga) | (c0.w ^ tga) |
              (c1.x ^ tga) | (c1.y ^ tga) | (c1.z ^ tga) | (c1.w ^ tga) |
              (c2.x ^ tga) | (c2.y ^ tga) | (c2.z ^ tga) | (c2.w ^ tga) |
              (c3.x ^ tga) | (c3.y ^ tga) | (c3.z ^ tga) | (c3.w ^ tga) |
              (c4.x ^ tga) | (c4.y ^ tga) | (c4.z ^ tga) | (c4.w ^ tga) |
              (c5.x ^ tga) | (c5.y ^ tga) | (c5.z ^ tga) | (c5.w ^ tga) |
              (c6.x ^ tga) | (c6.y ^ tga) | (c6.z ^ tga) | (c6.w ^ tga) |
              (c7.x ^ tga) | (c7.y ^ tga) | (c7.z ^ tga) | (c7.w ^ tga);
          if ((bad >> 16) == 0) break;
          __builtin_amdgcn_s_sleep(1);
        }
#define UNP(ci, idx)                                                         \
  { const unsigned wi = (unsigned)tid * 4u + (idx) * 1024u;                  \
    *(uint2*)&zs[wi >> 9][wi & 511u] =                                       \
        make_uint2((ci.x & 0xffffu) | (ci.y << 16),                          \
                   (ci.z & 0xffffu) | (ci.w << 16)); }
        UNP(c0, 0) UNP(c1, 1) UNP(c2, 2) UNP(c3, 3)
        UNP(c4, 4) UNP(c5, 5) UNP(c6, 6) UNP(c7, 7)
#undef UNP
      }
      // ---- x stage for this group's rows (zero in decode) ----
      if (t < kS) {
        const u32x4 xv = *(const u32x4*)(P.xb +
            ((size_t)(g * kGB + eb2) * kS + t) * kI + ec * 8);
        *(u32x4*)&zs[eb2][kH + ec * 8] = xv;
      } else {
        const u32x4 zv = {0u, 0u, 0u, 0u};
        *(u32x4*)&zs[eb2][kH + ec * 8] = zv;
      }
      __syncthreads();   // zs complete; also orders prev epilogue's outLDS reads

      // ---- GEMM: 3 (matrix, K-half) units per wave, M=16 ----
      {
        f32x4 a0c = {0.f,0.f,0.f,0.f}, a1c = {0.f,0.f,0.f,0.f}, a2c = {0.f,0.f,0.f,0.f};
#pragma unroll
        for (int i = 0; i < 10; ++i) {
          const int k0 = i * 32 + kq;
          bf16x8 alo = *(const bf16x8*)&zs[r][k0];          // K-half 0
          bf16x8 ahi = *(const bf16x8*)&zs[r][320 + k0];    // K-half 1
          a0c = MFMA(khs[0] ? ahi : alo, ld8(Wb[0] + k0), a0c);
          a1c = MFMA(khs[1] ? ahi : alo, ld8(Wb[1] + k0), a1c);
          a2c = MFMA(khs[2] ? ahi : alo, ld8(Wb[2] + k0), a2c);
        }
        f32x4 acc[3] = {a0c, a1c, a2c};
#pragma unroll
        for (int s = 0; s < 3; ++s) {
#pragma unroll
          for (int rr = 0; rr < 4; ++rr)
            outLDS[ums[s]][khs[s]][q * 4 + rr][r] = acc[s][rr];
        }
      }
      __syncthreads();   // outLDS ready

      // ---- epilogue: sum K-halves, gates, front, publish, shift, snapshot ----
      {
        const int b = g * kGB + eb2;
        const bool msk = (t >= kS) || (t < len_s[b]);
        float v[6];
#pragma unroll
        for (int m = 0; m < 6; ++m)
          v[m] = outLDS[m][0][eb2][ec] + outLDS[m][1][eb2][ec] + P.bias[m * kH + j];
        float hv = msk ? v[1] : v[0];
        float gt = msk ? v[3] : v[2];
        float gm = msk ? v[5] : v[4];
        float tau = 16.f * sigm(gt);
        tau = fminf(fmaxf(tau, 1.f), 16.f);
        float ml = sigm(gm);
        float front = bufr[g][1] + (ml / (1.f + fabsf(tau - 1.f))) * hv;
        __hip_bfloat16 hb = __float2bfloat16(front);
        unsigned short bits;
        __builtin_memcpy(&bits, &hb, 2);
        const unsigned word = (((unsigned)(t + 1)) << 16) | bits;
        __hip_atomic_store(hw + eb2 * 512 + j, word,
                           __ATOMIC_RELAXED, __HIP_MEMORY_SCOPE_AGENT);
        // shadow work
#pragma unroll
        for (int d = 1; d <= kMaxD; ++d) {
          float w = ml / (1.f + fabsf(tau - (float)d));
          bufr[g][d - 1] = bufr[g][d] + w * hv;
        }
        bufr[g][kMaxD] = 0.f;
        if ((unsigned)(t - (kS - 1)) < (unsigned)kOutL) {
          unsigned short* hp = (unsigned short*)(P.h0hist +
              ((size_t)(t - (kS - 1)) * kB + b) * kH + j);
          __hip_atomic_store(hp, bits, __ATOMIC_RELAXED, __HIP_MEMORY_SCOPE_AGENT);
        }
      }
      // no end-of-phase barrier: next phase's sync orders everything.
    }
  }

  // ---- tail: one grid barrier, then decode-output GEMM ----
  __builtin_amdgcn_s_waitcnt(0);
  __syncthreads();
  if (tid == 0)
    __hip_atomic_store(&P.arrive[wg * 16], 1, __ATOMIC_RELAXED, __HIP_MEMORY_SCOPE_AGENT);
  if (tid < kNWG) {
    while (__hip_atomic_load(&P.arrive[tid * 16],
                             __ATOMIC_RELAXED, __HIP_MEMORY_SCOPE_AGENT) < 1)
      __builtin_amdgcn_s_sleep(2);
  }
  __syncthreads();

  // dout[b][td][c] = h0hist[td][b][:] @ WtOut[c][:] + b_out[c]
  {
    const int mrow = wg * 64 + wave * 16 + r;   // m = td*32 + b
    const char* ap = (const char*)P.h0hist + (size_t)mrow * 1024 + q * 16;
    u32x4 d0, d1, d2, d3, d4, d5, d6, d7, d8, d9, dA, dB, dC, dD, dE, dF;
    asm volatile(
        "global_load_dwordx4 %0, %16, off sc0 sc1\n\t"
        "global_load_dwordx4 %1, %16, off offset:64 sc0 sc1\n\t"
        "global_load_dwordx4 %2, %16, off offset:128 sc0 sc1\n\t"
        "global_load_dwordx4 %3, %16, off offset:192 sc0 sc1\n\t"
        "global_load_dwordx4 %4, %16, off offset:256 sc0 sc1\n\t"
        "global_load_dwordx4 %5, %16, off offset:320 sc0 sc1\n\t"
        "global_load_dwordx4 %6, %16, off offset:384 sc0 sc1\n\t"
        "global_load_dwordx4 %7, %16, off offset:448 sc0 sc1\n\t"
        "global_load_dwordx4 %8, %16, off offset:512 sc0 sc1\n\t"
        "global_load_dwordx4 %9, %16, off offset:576 sc0 sc1\n\t"
        "global_load_dwordx4 %10, %16, off offset:640 sc0 sc1\n\t"
        "global_load_dwordx4 %11, %16, off offset:704 sc0 sc1\n\t"
        "global_load_dwordx4 %12, %16, off offset:768 sc0 sc1\n\t"
        "global_load_dwordx4 %13, %16, off offset:832 sc0 sc1\n\t"
        "global_load_dwordx4 %14, %16, off offset:896 sc0 sc1\n\t"
        "global_load_dwordx4 %15, %16, off offset:960 sc0 sc1\n\t"
        "s_waitcnt vmcnt(0)"
        : "=&v"(d0), "=&v"(d1), "=&v"(d2), "=&v"(d3),
          "=&v"(d4), "=&v"(d5), "=&v"(d6), "=&v"(d7),
          "=&v"(d8), "=&v"(d9), "=&v"(dA), "=&v"(dB),
          "=&v"(dC), "=&v"(dD), "=&v"(dE), "=&v"(dF)
        : "v"(ap)
        : "memory");
    union { u32x4 u; bf16x8 v; } av[16] = {{d0},{d1},{d2},{d3},{d4},{d5},{d6},{d7},
                                           {d8},{d9},{dA},{dB},{dC},{dD},{dE},{dF}};
    f32x4 T0 = {0.f,0.f,0.f,0.f}, T1 = {0.f,0.f,0.f,0.f};
    f32x4 T2 = {0.f,0.f,0.f,0.f}, T3 = {0.f,0.f,0.f,0.f};
#pragma unroll
    for (int ik = 0; ik < 16; ++ik) {
      const int kk = ik * 32 + kq;
      const __hip_bfloat16* wb = P.WtOut + (size_t)r * kH + kk;
      T0 = MFMA(av[ik].v, ld8(wb), T0);
      T1 = MFMA(av[ik].v, ld8(wb + 16 * kH), T1);
      T2 = MFMA(av[ik].v, ld8(wb + 32 * kH), T2);
      T3 = MFMA(av[ik].v, ld8(wb + 48 * kH), T3);
    }
    f32x4 T[4] = {T0, T1, T2, T3};
#pragma unroll
    for (int ct = 0; ct < 4; ++ct) {
      const int c = ct * 16 + r;
      const float bo = P.b_out[c];
#pragma unroll
      for (int rr = 0; rr < 4; ++rr) {
        const int m = wg * 64 + wave * 16 + q * 4 + rr;
        const int b = m & 31, td = m >> 5;
        P.dout[(size_t)b * (kOutL * kC) + td * kC + c] = T[ct][rr] + bo;
      }
    }
  }
}

extern "C" void kernel_launch(void* const* d_in, const int* in_sizes, int n_in,
                              void* d_out, int out_size, void* d_ws, size_t ws_size,
                              hipStream_t stream) {
  const float* x      = (const float*)d_in[0];
  const int*   lens   = (const int*)d_in[1];
  const float* W_in   = (const float*)d_in[3];
  const float* b_in   = (const float*)d_in[4];
  const float* W_pass = (const float*)d_in[5];
  const float* b_pass = (const float*)d_in[6];
  const float* W_tau  = (const float*)d_in[7];
  const float* b_tau  = (const float*)d_in[8];
  const float* W_mem  = (const float*)d_in[9];
  const float* b_mem  = (const float*)d_in[10];
  const float* W_out  = (const float*)d_in[11];
  const float* b_out  = (const float*)d_in[12];

  char* ws = (char*)d_ws;
  size_t off = 0;
  int* arrive = (int*)(ws + off);                  off += 2048;
  unsigned* hg = (unsigned*)(ws + off);            off += (size_t)4 * 8192 * 4;  // 128KB
  float* bias = (float*)(ws + off);                off += 6 * kH * sizeof(float);
  __hip_bfloat16* WtOut = (__hip_bfloat16*)(ws + off); off += (size_t)kC * kH * 2;
  __hip_bfloat16* h0hist = (__hip_bfloat16*)(ws + off); off += (size_t)kOutL * kB * kH * 2;
  __hip_bfloat16* xb    = (__hip_bfloat16*)(ws + off); off += (size_t)kB * kS * kI * 2;
  __hip_bfloat16* Wall  = (__hip_bfloat16*)(ws + off); off += (size_t)6 * kH * kKz * 2;
  __hip_bfloat16* BtP   = (__hip_bfloat16*)(ws + off); off += (size_t)kH * kH * 2;
  __hip_bfloat16* BtT   = (__hip_bfloat16*)(ws + off); off += (size_t)kH * kH * 2;
  __hip_bfloat16* BtM   = (__hip_bfloat16*)(ws + off); off += (size_t)kH * kH * 2;
  __hip_bfloat16* Cip   = (__hip_bfloat16*)(ws + off); off += (size_t)kKz * kH * 2;

  // zero barrier flags + all four tagged h0 images (tag 0 == step-0 expectation)
  hipMemsetAsync(d_ws, 0, 2048 + (size_t)4 * 8192 * 4, stream);

  prep_cast<<<512, 256, 0, stream>>>(x, W_in, W_pass, W_tau, W_mem, W_out,
                                     xb, Wall, BtP, BtT, BtM, WtOut);
  prep_bias<<<1, 512, 0, stream>>>(b_in, b_pass, b_tau, b_mem, W_pass, W_tau, W_mem, bias);
  prep_mm1<<<dim3(40, 32, 3), 64, 0, stream>>>(W_in, BtP, BtT, BtM, Wall, Cip);
  prep_mm2<<<dim3(40, 32, 2), 64, 0, stream>>>(Cip, BtT, BtM, Wall);

  KParams P;
  P.xb = xb; P.Wall = Wall; P.WtOut = WtOut; P.bias = bias; P.b_out = b_out;
  P.hg = hg; P.h0hist = h0hist; P.arrive = arrive;
  P.lengths = lens; P.dout = (float*)d_out;

  rnn_main<<<dim3(kNWG), dim3(256), 0, stream>>>(P);
}

// Round 14
// 2542.055 us; speedup vs baseline: 1.3754x; 1.3754x over previous
//
#include <hip/hip_runtime.h>
#include <hip/hip_bf16.h>

// DelayRNN on MI355X — Round 14 = Round 12 verbatim (best measured: 2544us).
// R13's batch-group pipelining falsified the "hide RTT behind compute" idea
// (two exchange phases/step = two RTTs; 3.5ms). The R5/R12 structure — ONE
// fused detect+fetch coherence hop per step (tagged self-validating words, no
// producer barrier), critical-path-first epilogue, tail decode GEMM — sits at
// the measured structural floor: step = RTT(~5.4us) + W(~2us).

constexpr int kB    = 32;
constexpr int kS    = 256;
constexpr int kI    = 128;
constexpr int kH    = 512;
constexpr int kC    = 64;
constexpr int kOutL = 64;
constexpr int kMaxD = 16;
constexpr int kBufD = 17;
constexpr int kNWG  = 32;
constexpr int kJPW  = 16;
constexpr int kSteps = kS + kOutL;   // 320
constexpr int kKz   = kH + kI;       // 640
constexpr int kZPad = 8;             // zs row stride 648 elem (1296 B)

typedef __bf16 bf16x8 __attribute__((ext_vector_type(8)));
typedef float  f32x4  __attribute__((ext_vector_type(4)));
typedef unsigned int u32x4 __attribute__((ext_vector_type(4)));

__device__ __forceinline__ f32x4 MFMA(bf16x8 a, bf16x8 b, f32x4 c) {
  return __builtin_amdgcn_mfma_f32_16x16x32_bf16(a, b, c, 0, 0, 0);
}
__device__ __forceinline__ bf16x8 ld8(const __hip_bfloat16* p) {
  return *reinterpret_cast<const bf16x8*>(p);
}
__device__ __forceinline__ bf16x8 ld8_f32(const float* p) {
  float4 a = *(const float4*)p, b = *(const float4*)(p + 4);
  union { __hip_bfloat16 h[8]; bf16x8 v; } c;
  c.h[0] = __float2bfloat16(a.x); c.h[1] = __float2bfloat16(a.y);
  c.h[2] = __float2bfloat16(a.z); c.h[3] = __float2bfloat16(a.w);
  c.h[4] = __float2bfloat16(b.x); c.h[5] = __float2bfloat16(b.y);
  c.h[6] = __float2bfloat16(b.z); c.h[7] = __float2bfloat16(b.w);
  return c.v;
}
__device__ __forceinline__ float sigm(float x) { return 1.0f / (1.0f + __expf(-x)); }

// ---------------- prep kernels (validated R2-R12) ----------------

__global__ void prep_cast(const float* x, const float* W_in, const float* W_pass,
                          const float* W_tau, const float* W_mem, const float* W_out,
                          __hip_bfloat16* xb, __hip_bfloat16* Wall, __hip_bfloat16* BtP,
                          __hip_bfloat16* BtT, __hip_bfloat16* BtM, __hip_bfloat16* WtOut) {
  const int tid = blockIdx.x * blockDim.x + threadIdx.x;
  const int nth = gridDim.x * blockDim.x;
  for (int i = tid; i < kB * kS * kI; i += nth) xb[i] = __float2bfloat16(x[i]);
  for (int i = tid; i < kH * kKz; i += nth) {
    int j = i / kKz, k = i - j * kKz;
    Wall[i] = __float2bfloat16(W_in[k * kH + j]);
  }
  for (int i = tid; i < kH * kH; i += nth) {
    int j = i >> 9, k = i & 511;
    BtP[i] = __float2bfloat16(W_pass[k * kH + j]);
    BtT[i] = __float2bfloat16(W_tau[k * kH + j]);
    BtM[i] = __float2bfloat16(W_mem[k * kH + j]);
  }
  for (int i = tid; i < kC * kH; i += nth) {
    int c = i >> 9, k = i & 511;
    WtOut[i] = __float2bfloat16(W_out[k * kC + c]);
  }
}

__global__ void prep_bias(const float* b_in, const float* b_pass, const float* b_tau,
                          const float* b_mem, const float* W_pass, const float* W_tau,
                          const float* W_mem, float* bias) {
  __shared__ float bp_s[kH];
  const int j = threadIdx.x;
  float s1 = 0.f, s2 = 0.f, s3 = 0.f;
  for (int k = 0; k < kH; ++k) {
    float bi = b_in[k];
    s1 += bi * W_pass[k * kH + j];
    s2 += bi * W_tau[k * kH + j];
    s3 += bi * W_mem[k * kH + j];
  }
  float bP = s1 + b_pass[j];
  bias[j]          = b_in[j];
  bias[kH + j]     = bP;
  bias[2 * kH + j] = s2 + b_tau[j];
  bias[4 * kH + j] = s3 + b_mem[j];
  bp_s[j] = bP;
  __syncthreads();
  float s4 = 0.f, s5 = 0.f;
  for (int k = 0; k < kH; ++k) {
    float v = bp_s[k];
    s4 += v * W_tau[k * kH + j];
    s5 += v * W_mem[k * kH + j];
  }
  bias[3 * kH + j] = s4 + b_tau[j];
  bias[5 * kH + j] = s5 + b_mem[j];
}

__global__ __launch_bounds__(64) void prep_mm1(const float* W_in, const __hip_bfloat16* BtP,
    const __hip_bfloat16* BtT, const __hip_bfloat16* BtM,
    __hip_bfloat16* Wall, __hip_bfloat16* Cip) {
  const int bm = blockIdx.x, bn = blockIdx.y, z = blockIdx.z;
  const int lane = threadIdx.x;
  const int kq = (lane >> 4) * 8;
  const __hip_bfloat16* Bt = (z == 0) ? BtP : (z == 1 ? BtT : BtM);
  const int mat = (z == 0) ? 1 : (z == 1 ? 2 : 4);
  const float* arow = W_in + (size_t)(bm * 16 + (lane & 15)) * kH;
  const __hip_bfloat16* brow = Bt + (size_t)(bn * 16 + (lane & 15)) * kH;
  f32x4 acc = {0.f, 0.f, 0.f, 0.f};
  for (int i = 0; i < 16; ++i) {
    const int kk = i * 32 + kq;
    acc = MFMA(ld8_f32(arow + kk), ld8(brow + kk), acc);
  }
  const int rm = (lane >> 4) * 4, cn = lane & 15;
  union { __hip_bfloat16 h[4]; ushort4 s; } cv;
#pragma unroll
  for (int r = 0; r < 4; ++r) cv.h[r] = __float2bfloat16(acc[r]);
  __hip_bfloat16* wd = Wall + ((size_t)mat * kH + bn * 16 + cn) * kKz + bm * 16 + rm;
  *(ushort4*)wd = cv.s;
  if (z == 0) {
#pragma unroll
    for (int r = 0; r < 4; ++r)
      Cip[(size_t)(bm * 16 + rm + r) * kH + bn * 16 + cn] = cv.h[r];
  }
}

__global__ __launch_bounds__(64) void prep_mm2(const __hip_bfloat16* Cip,
    const __hip_bfloat16* BtT, const __hip_bfloat16* BtM, __hip_bfloat16* Wall) {
  const int bm = blockIdx.x, bn = blockIdx.y, z = blockIdx.z;
  const int lane = threadIdx.x;
  const int kq = (lane >> 4) * 8;
  const __hip_bfloat16* Bt = (z == 0) ? BtT : BtM;
  const int mat = (z == 0) ? 3 : 5;
  const __hip_bfloat16* arow = Cip + (size_t)(bm * 16 + (lane & 15)) * kH;
  const __hip_bfloat16* brow = Bt + (size_t)(bn * 16 + (lane & 15)) * kH;
  f32x4 acc = {0.f, 0.f, 0.f, 0.f};
  for (int i = 0; i < 16; ++i) {
    const int kk = i * 32 + kq;
    acc = MFMA(ld8(arow + kk), ld8(brow + kk), acc);
  }
  const int rm = (lane >> 4) * 4, cn = lane & 15;
  union { __hip_bfloat16 h[4]; ushort4 s; } cv;
#pragma unroll
  for (int r = 0; r < 4; ++r) cv.h[r] = __float2bfloat16(acc[r]);
  __hip_bfloat16* wd = Wall + ((size_t)mat * kH + bn * 16 + cn) * kKz + bm * 16 + rm;
  *(ushort4*)wd = cv.s;
}

// ---------------- main persistent kernel ----------------

struct KParams {
  const __hip_bfloat16* xb;       // bf16 input [B][S][I]
  const __hip_bfloat16* Wall;     // [6][512][640] composites, [col][k]
  const __hip_bfloat16* WtOut;    // [64][512]
  const float* bias;              // [6][512]
  const float* b_out;             // [64]
  unsigned* h0a;                  // ping: [32][512] tagged words
  unsigned* h0b;                  // pong
  __hip_bfloat16* h0hist;         // [64][32][512] decode-entry snapshots
  int* arrive;                    // tail-barrier flags, 64B stride
  const int* lengths;
  float* dout;                    // [B][kOutL][C]
};

__global__ __launch_bounds__(256, 1) void rnn_main(KParams P) {
  __shared__ __align__(16) __hip_bfloat16 zs[kB][kKz + kZPad];  // 41,472 B
  __shared__ float outLDS[6][kB][kJPW + 1];                     // 13,056 B
  __shared__ int   len_s[kB];

  const int wg = blockIdx.x, tid = threadIdx.x;
  const int lane = tid & 63, wave = tid >> 6;
  const int kq = (lane >> 4) * 8;
  const int jn = wg * kJPW + (lane & 15);
  // unit partition: wave w owns units {3w..3w+2}, unit u=(mat u>>1, half u&1)
  const int u0m = (3 * wave) >> 1, u2m = (3 * wave + 2) >> 1;
  const __hip_bfloat16* WbA = P.Wall + ((size_t)u0m * kH + jn) * kKz;
  const __hip_bfloat16* WbC = P.Wall + ((size_t)u2m * kH + jn) * kKz;
  const bool wodd = wave & 1;
  const int eb = tid >> 3, eq = tid & 7;      // epilogue: batch, col-pair
  const int xrow = tid >> 3, xch = tid & 7;   // x staging geometry

  float bufr[2][kBufD];
#pragma unroll
  for (int u = 0; u < 2; ++u)
#pragma unroll
    for (int d = 0; d < kBufD; ++d) bufr[u][d] = 0.f;

  if (tid < kB) len_s[tid] = P.lengths[tid];

  // stage x(0)
#pragma unroll
  for (int i = 0; i < 2; ++i) {
    const int c2 = i * 8 + xch;
    const u32x4 xv = *(const u32x4*)(P.xb + ((size_t)xrow * kS + 0) * kI + c2 * 8);
    *(u32x4*)&zs[xrow][kH + c2 * 8] = xv;
  }

  const unsigned o0 = tid * 16u;

  for (int t = 0; t < kSteps; ++t) {
    const unsigned* h0r = (t & 1) ? P.h0b : P.h0a;
    unsigned*       h0w = (t & 1) ? P.h0a : P.h0b;

    // ---- fused detect+fetch: poll tagged words until all tags == t ----
    {
      const unsigned tga = ((unsigned)t) << 16;
      u32x4 c0, c1, c2, c3, c4, c5, c6, c7, c8, c9, cA, cB, cC, cD, cE, cF;
      for (;;) {
        asm volatile(
            "global_load_dwordx4 %0, %16, %32 sc0 sc1\n\t"
            "global_load_dwordx4 %1, %17, %32 sc0 sc1\n\t"
            "global_load_dwordx4 %2, %18, %32 sc0 sc1\n\t"
            "global_load_dwordx4 %3, %19, %32 sc0 sc1\n\t"
            "global_load_dwordx4 %4, %20, %32 sc0 sc1\n\t"
            "global_load_dwordx4 %5, %21, %32 sc0 sc1\n\t"
            "global_load_dwordx4 %6, %22, %32 sc0 sc1\n\t"
            "global_load_dwordx4 %7, %23, %32 sc0 sc1\n\t"
            "global_load_dwordx4 %8, %24, %32 sc0 sc1\n\t"
            "global_load_dwordx4 %9, %25, %32 sc0 sc1\n\t"
            "global_load_dwordx4 %10, %26, %32 sc0 sc1\n\t"
            "global_load_dwordx4 %11, %27, %32 sc0 sc1\n\t"
            "global_load_dwordx4 %12, %28, %32 sc0 sc1\n\t"
            "global_load_dwordx4 %13, %29, %32 sc0 sc1\n\t"
            "global_load_dwordx4 %14, %30, %32 sc0 sc1\n\t"
            "global_load_dwordx4 %15, %31, %32 sc0 sc1\n\t"
            "s_waitcnt vmcnt(0)"
            : "=&v"(c0), "=&v"(c1), "=&v"(c2), "=&v"(c3),
              "=&v"(c4), "=&v"(c5), "=&v"(c6), "=&v"(c7),
              "=&v"(c8), "=&v"(c9), "=&v"(cA), "=&v"(cB),
              "=&v"(cC), "=&v"(cD), "=&v"(cE), "=&v"(cF)
            : "v"(o0), "v"(o0 + 4096u), "v"(o0 + 8192u), "v"(o0 + 12288u),
              "v"(o0 + 16384u), "v"(o0 + 20480u), "v"(o0 + 24576u), "v"(o0 + 28672u),
              "v"(o0 + 32768u), "v"(o0 + 36864u), "v"(o0 + 40960u), "v"(o0 + 45056u),
              "v"(o0 + 49152u), "v"(o0 + 53248u), "v"(o0 + 57344u), "v"(o0 + 61440u),
              "s"(h0r)
            : "memory");
        // 8B atomic publish => tags within each 8B pair identical: check .x/.z
        unsigned bad =
            (c0.x ^ tga) | (c0.z ^ tga) | (c1.x ^ tga) | (c1.z ^ tga) |
            (c2.x ^ tga) | (c2.z ^ tga) | (c3.x ^ tga) | (c3.z ^ tga) |
            (c4.x ^ tga) | (c4.z ^ tga) | (c5.x ^ tga) | (c5.z ^ tga) |
            (c6.x ^ tga) | (c6.z ^ tga) | (c7.x ^ tga) | (c7.z ^ tga) |
            (c8.x ^ tga) | (c8.z ^ tga) | (c9.x ^ tga) | (c9.z ^ tga) |
            (cA.x ^ tga) | (cA.z ^ tga) | (cB.x ^ tga) | (cB.z ^ tga) |
            (cC.x ^ tga) | (cC.z ^ tga) | (cD.x ^ tga) | (cD.z ^ tga) |
            (cE.x ^ tga) | (cE.z ^ tga) | (cF.x ^ tga) | (cF.z ^ tga);
        if ((bad >> 16) == 0) break;
        __builtin_amdgcn_s_sleep(1);
      }
#define UNP(ci, idx)                                                         \
  { const unsigned ch = (idx)*256u + (unsigned)tid;                          \
    *(uint2*)&zs[ch >> 7][(ch & 127u) * 4] =                                 \
        make_uint2((ci.x & 0xffffu) | (ci.y << 16),                          \
                   (ci.z & 0xffffu) | (ci.w << 16)); }
      UNP(c0, 0)  UNP(c1, 1)  UNP(c2, 2)  UNP(c3, 3)
      UNP(c4, 4)  UNP(c5, 5)  UNP(c6, 6)  UNP(c7, 7)
      UNP(c8, 8)  UNP(c9, 9)  UNP(cA, 10) UNP(cB, 11)
      UNP(cC, 12) UNP(cD, 13) UNP(cE, 14) UNP(cF, 15)
#undef UNP
    }
    __syncthreads();

    // ---- unit-partitioned GEMM: 3 units/wave, full K=640 ----
    {
      f32x4 A0 = {0.f,0.f,0.f,0.f}, A1 = {0.f,0.f,0.f,0.f}, A2 = {0.f,0.f,0.f,0.f};
      const int rlo = lane & 15, rhi = 16 + (lane & 15);
      if (!wodd) {
#pragma unroll
        for (int i = 0; i < 20; ++i) {
          const int kk = i * 32 + kq;
          bf16x8 alo = *(const bf16x8*)&zs[rlo][kk];
          bf16x8 ahi = *(const bf16x8*)&zs[rhi][kk];
          bf16x8 b0 = ld8(WbA + kk), b2 = ld8(WbC + kk);
          A0 = MFMA(alo, b0, A0);
          A1 = MFMA(ahi, b0, A1);
          A2 = MFMA(alo, b2, A2);
        }
      } else {
#pragma unroll
        for (int i = 0; i < 20; ++i) {
          const int kk = i * 32 + kq;
          bf16x8 alo = *(const bf16x8*)&zs[rlo][kk];
          bf16x8 ahi = *(const bf16x8*)&zs[rhi][kk];
          bf16x8 b0 = ld8(WbA + kk), b2 = ld8(WbC + kk);
          A0 = MFMA(ahi, b0, A0);
          A1 = MFMA(alo, b2, A1);
          A2 = MFMA(ahi, b2, A2);
        }
      }
      f32x4 acc[3] = {A0, A1, A2};
#pragma unroll
      for (int s = 0; s < 3; ++s) {
        const int u = 3 * wave + s;
        const int m = u >> 1, rb = (u & 1) * 16;
#pragma unroll
        for (int r = 0; r < 4; ++r)
          outLDS[m][rb + (lane >> 4) * 4 + r][lane & 15] = acc[s][r];
      }
    }
    __syncthreads();

    // ---- epilogue 1 (critical path): gates -> front -> tagged publish ----
    const bool msk = (t >= kS) || (t < len_s[eb]);
    float hv2[2], tau2[2], ml2[2];
    unsigned short bits[2];
#pragma unroll
    for (int u = 0; u < 2; ++u) {
      const int jl = eq * 2 + u, j = wg * kJPW + jl;
      float hp = outLDS[0][eb][jl] + P.bias[j];
      float pv = outLDS[1][eb][jl] + P.bias[kH + j];
      float ta = outLDS[2][eb][jl] + P.bias[2 * kH + j];
      float tb = outLDS[3][eb][jl] + P.bias[3 * kH + j];
      float ma = outLDS[4][eb][jl] + P.bias[4 * kH + j];
      float mb = outLDS[5][eb][jl] + P.bias[5 * kH + j];
      float hv = msk ? pv : hp;
      float gt = msk ? tb : ta;
      float gm = msk ? mb : ma;
      float tau = 16.f * sigm(gt);
      tau = fminf(fmaxf(tau, 1.f), 16.f);
      float ml = sigm(gm);
      hv2[u] = hv; tau2[u] = tau; ml2[u] = ml;
      float front = bufr[u][1] + (ml / (1.f + fabsf(tau - 1.f))) * hv;
      __hip_bfloat16 hb = __float2bfloat16(front);
      unsigned short bt;
      __builtin_memcpy(&bt, &hb, 2);
      bits[u] = bt;
    }
    {
      const unsigned tagp = ((unsigned)(t + 1)) << 16;
      const unsigned lo = tagp | bits[0], hi = tagp | bits[1];
      const unsigned long long pk = ((unsigned long long)hi << 32) | lo;
      __hip_atomic_store((unsigned long long*)(h0w + eb * kH + wg * kJPW + eq * 2),
                         pk, __ATOMIC_RELAXED, __HIP_MEMORY_SCOPE_AGENT);
    }

    // ---- epilogue 2 (in the shadow): shift, snapshot, x prefetch ----
#pragma unroll
    for (int u = 0; u < 2; ++u) {
#pragma unroll
      for (int d = 1; d <= kMaxD; ++d) {
        float w = ml2[u] / (1.f + fabsf(tau2[u] - (float)d));
        bufr[u][d - 1] = bufr[u][d] + w * hv2[u];
      }
      bufr[u][kMaxD] = 0.f;
    }
    if ((unsigned)(t - (kS - 1)) < (unsigned)kOutL) {
      const unsigned hv = ((unsigned)bits[1] << 16) | bits[0];
      unsigned* hp = (unsigned*)(P.h0hist + ((size_t)(t - (kS - 1)) * kB + eb) * kH)
                     + (wg * 8 + eq);
      __hip_atomic_store(hp, hv, __ATOMIC_RELAXED, __HIP_MEMORY_SCOPE_AGENT);
    }
    const int tn = t + 1;
    if (tn < kS) {
#pragma unroll
      for (int i = 0; i < 2; ++i) {
        const int c2 = i * 8 + xch;
        const u32x4 xv = *(const u32x4*)(P.xb + ((size_t)xrow * kS + tn) * kI + c2 * 8);
        *(u32x4*)&zs[xrow][kH + c2 * 8] = xv;
      }
    } else if (tn == kS) {
      const u32x4 zv = {0u, 0u, 0u, 0u};
#pragma unroll
      for (int i = 0; i < 2; ++i) {
        const int c2 = i * 8 + xch;
        *(u32x4*)&zs[xrow][kH + c2 * 8] = zv;
      }
    }
    // no barrier: dataflow tags order everything across WGs.
  }

  // ---- tail: one grid barrier, then decode-output GEMM ----
  __builtin_amdgcn_s_waitcnt(0);
  __syncthreads();
  if (tid == 0)
    __hip_atomic_store(&P.arrive[wg * 16], 1, __ATOMIC_RELAXED, __HIP_MEMORY_SCOPE_AGENT);
  if (tid < kNWG) {
    while (__hip_atomic_load(&P.arrive[tid * 16],
                             __ATOMIC_RELAXED, __HIP_MEMORY_SCOPE_AGENT) < 1)
      __builtin_amdgcn_s_sleep(2);
  }
  __syncthreads();

  // dout[b][td][c] = h0hist[td][b][:] @ WtOut[c][:] + b_out[c]
  {
    const int q = lane >> 4, r = lane & 15;
    const int mrow = wg * 64 + wave * 16 + r;   // m = td*32 + b
    const char* ap = (const char*)P.h0hist + (size_t)mrow * 1024 + q * 16;
    u32x4 d0, d1, d2, d3, d4, d5, d6, d7, d8, d9, dA, dB, dC, dD, dE, dF;
    asm volatile(
        "global_load_dwordx4 %0, %16, off sc0 sc1\n\t"
        "global_load_dwordx4 %1, %16, off offset:64 sc0 sc1\n\t"
        "global_load_dwordx4 %2, %16, off offset:128 sc0 sc1\n\t"
        "global_load_dwordx4 %3, %16, off offset:192 sc0 sc1\n\t"
        "global_load_dwordx4 %4, %16, off offset:256 sc0 sc1\n\t"
        "global_load_dwordx4 %5, %16, off offset:320 sc0 sc1\n\t"
        "global_load_dwordx4 %6, %16, off offset:384 sc0 sc1\n\t"
        "global_load_dwordx4 %7, %16, off offset:448 sc0 sc1\n\t"
        "global_load_dwordx4 %8, %16, off offset:512 sc0 sc1\n\t"
        "global_load_dwordx4 %9, %16, off offset:576 sc0 sc1\n\t"
        "global_load_dwordx4 %10, %16, off offset:640 sc0 sc1\n\t"
        "global_load_dwordx4 %11, %16, off offset:704 sc0 sc1\n\t"
        "global_load_dwordx4 %12, %16, off offset:768 sc0 sc1\n\t"
        "global_load_dwordx4 %13, %16, off offset:832 sc0 sc1\n\t"
        "global_load_dwordx4 %14, %16, off offset:896 sc0 sc1\n\t"
        "global_load_dwordx4 %15, %16, off offset:960 sc0 sc1\n\t"
        "s_waitcnt vmcnt(0)"
        : "=&v"(d0), "=&v"(d1), "=&v"(d2), "=&v"(d3),
          "=&v"(d4), "=&v"(d5), "=&v"(d6), "=&v"(d7),
          "=&v"(d8), "=&v"(d9), "=&v"(dA), "=&v"(dB),
          "=&v"(dC), "=&v"(dD), "=&v"(dE), "=&v"(dF)
        : "v"(ap)
        : "memory");
    union { u32x4 u; bf16x8 v; } av[16] = {{d0},{d1},{d2},{d3},{d4},{d5},{d6},{d7},
                                           {d8},{d9},{dA},{dB},{dC},{dD},{dE},{dF}};
    f32x4 T0 = {0.f,0.f,0.f,0.f}, T1 = {0.f,0.f,0.f,0.f};
    f32x4 T2 = {0.f,0.f,0.f,0.f}, T3 = {0.f,0.f,0.f,0.f};
#pragma unroll
    for (int ik = 0; ik < 16; ++ik) {
      const int kk = ik * 32 + kq;
      const __hip_bfloat16* wb = P.WtOut + (size_t)r * kH + kk;
      T0 = MFMA(av[ik].v, ld8(wb), T0);
      T1 = MFMA(av[ik].v, ld8(wb + 16 * kH), T1);
      T2 = MFMA(av[ik].v, ld8(wb + 32 * kH), T2);
      T3 = MFMA(av[ik].v, ld8(wb + 48 * kH), T3);
    }
    f32x4 T[4] = {T0, T1, T2, T3};
#pragma unroll
    for (int ct = 0; ct < 4; ++ct) {
      const int c = ct * 16 + r;
      const float bo = P.b_out[c];
#pragma unroll
      for (int rr = 0; rr < 4; ++rr) {
        const int m = wg * 64 + wave * 16 + q * 4 + rr;
        const int b = m & 31, td = m >> 5;
        P.dout[(size_t)b * (kOutL * kC) + td * kC + c] = T[ct][rr] + bo;
      }
    }
  }
}

extern "C" void kernel_launch(void* const* d_in, const int* in_sizes, int n_in,
                              void* d_out, int out_size, void* d_ws, size_t ws_size,
                              hipStream_t stream) {
  const float* x      = (const float*)d_in[0];
  const int*   lens   = (const int*)d_in[1];
  const float* W_in   = (const float*)d_in[3];
  const float* b_in   = (const float*)d_in[4];
  const float* W_pass = (const float*)d_in[5];
  const float* b_pass = (const float*)d_in[6];
  const float* W_tau  = (const float*)d_in[7];
  const float* b_tau  = (const float*)d_in[8];
  const float* W_mem  = (const float*)d_in[9];
  const float* b_mem  = (const float*)d_in[10];
  const float* W_out  = (const float*)d_in[11];
  const float* b_out  = (const float*)d_in[12];

  char* ws = (char*)d_ws;
  size_t off = 0;
  int* arrive = (int*)(ws + off);                  off += 2048;
  unsigned* h0a = (unsigned*)(ws + off);           off += (size_t)kB * kH * 4;   // 64KB
  unsigned* h0b = (unsigned*)(ws + off);           off += (size_t)kB * kH * 4;   // 64KB
  float* bias = (float*)(ws + off);                off += 6 * kH * sizeof(float);
  __hip_bfloat16* WtOut = (__hip_bfloat16*)(ws + off); off += (size_t)kC * kH * 2;
  __hip_bfloat16* h0hist = (__hip_bfloat16*)(ws + off); off += (size_t)kOutL * kB * kH * 2;
  __hip_bfloat16* xb    = (__hip_bfloat16*)(ws + off); off += (size_t)kB * kS * kI * 2;
  __hip_bfloat16* Wall  = (__hip_bfloat16*)(ws + off); off += (size_t)6 * kH * kKz * 2;
  __hip_bfloat16* BtP   = (__hip_bfloat16*)(ws + off); off += (size_t)kH * kH * 2;
  __hip_bfloat16* BtT   = (__hip_bfloat16*)(ws + off); off += (size_t)kH * kH * 2;
  __hip_bfloat16* BtM   = (__hip_bfloat16*)(ws + off); off += (size_t)kH * kH * 2;
  __hip_bfloat16* Cip   = (__hip_bfloat16*)(ws + off); off += (size_t)kKz * kH * 2;

  // zero barrier flags + both tagged h0 buffers (tag 0 == step-0 expectation)
  hipMemsetAsync(d_ws, 0, 2048 + 2 * (size_t)kB * kH * 4, stream);

  prep_cast<<<512, 256, 0, stream>>>(x, W_in, W_pass, W_tau, W_mem, W_out,
                                     xb, Wall, BtP, BtT, BtM, WtOut);
  prep_bias<<<1, 512, 0, stream>>>(b_in, b_pass, b_tau, b_mem, W_pass, W_tau, W_mem, bias);
  prep_mm1<<<dim3(40, 32, 3), 64, 0, stream>>>(W_in, BtP, BtT, BtM, Wall, Cip);
  prep_mm2<<<dim3(40, 32, 2), 64, 0, stream>>>(Cip, BtT, BtM, Wall);

  KParams P;
  P.xb = xb; P.Wall = Wall; P.WtOut = WtOut; P.bias = bias; P.b_out = b_out;
  P.h0a = h0a; P.h0b = h0b; P.h0hist = h0hist; P.arrive = arrive;
  P.lengths = lens; P.dout = (float*)d_out;

  rnn_main<<<dim3(kNWG), dim3(256), 0, stream>>>(P);
}